// Round 15
// baseline (165.027 us; speedup 1.0000x reference)
//
#include <hip/hip_runtime.h>
#include <hip/hip_cooperative_groups.h>

namespace cg = cooperative_groups;

#define K_TOP  300
#define NCLS   80
#define NB     256
#define NF4    20000       // float4 per batch (80000 floats)
#define GTHR   2.2f        // static collect threshold; rank-300 sits at z~2.67
#define BPB    4           // collect blocks per batch
#define CHUNKF 5000        // float4 per collect block
#define WAVEF  1250        // float4 per wave (19 full rounds of 64 + 34 tail)
#define SEGC   128         // per-wave segment capacity (expect ~70 +/- 8.3, 7 sigma)
#define NSEG   16          // segments per batch (BPB blocks x 4 waves)
#define NCAND  2048        // NSEG*SEGC
#define NBK    1024        // bucket count

typedef unsigned int       u32;
typedef unsigned long long u64;

__device__ __forceinline__ u32 order_f32(float f) {
    u32 u = __float_as_uint(f);
    return u ^ ((u >> 31) ? 0xFFFFFFFFu : 0x80000000u);
}
__device__ __forceinline__ float unorder_f32(u32 u) {
    u32 v = (u & 0x80000000u) ? (u ^ 0x80000000u) : ~u;
    return __uint_as_float(v);
}

// fine bucket: (o>>14) - bias, clamped to [0,1023]; monotone in key
__device__ __forceinline__ u32 fbucket(u64 key, u32 bias14) {
    u32 d = (u32)(key >> 46) - bias14;
    return (d > 1023u) ? 1023u : d;
}

// ballot-aggregated per-wave store: wave-uniform cursor, no atomics
__device__ __forceinline__ u32 wstore(float v, int idx, u64* __restrict__ seg,
                                      u32 cursor, int lane) {
    const bool win = (v >= GTHR);
    const u64 mask = __ballot(win);
    if (mask) {
        if (win) {
            u32 pos = cursor + (u32)__popcll(mask & ((1ull << lane) - 1ull));
            if (pos < SEGC) {
                u32 o = order_f32(v);
                seg[pos] = ((u64)o << 32) | (u64)(0xFFFFFFFFu - (u32)idx);
            }
        }
        cursor += (u32)__popcll(mask);
    }
    return cursor;
}
__device__ __forceinline__ u32 wstore4(float4 v, int i4, u64* __restrict__ seg,
                                       u32 cursor, int lane) {
    cursor = wstore(v.x, i4 + 0, seg, cursor, lane);
    cursor = wstore(v.y, i4 + 1, seg, cursor, lane);
    cursor = wstore(v.z, i4 + 2, seg, cursor, lane);
    cursor = wstore(v.w, i4 + 3, seg, cursor, lane);
    return cursor;
}

// exclusive-suffix scan over NBK=1024 buckets, 256 threads (4 buckets/thread,
// 16-bucket groups). On return hist[bk]=cur[bk]=start, *s_B = max bk with
// suffix(>=bk) >= K_TOP. Caller barriers before/after. (proven R9/R10)
__device__ __forceinline__ void scan_buckets(u32* hist, u32* cur, u32* csum,
                                             int* s_B, int t) {
    if (t < 64) {
        u32 s = 0;
        for (int u = 0; u < 16; ++u) s += hist[16*t + u];
        csum[t] = s;
    }
    __syncthreads();
    if (t == 0) {
        u32 run = 0;
        for (int s = 63; s >= 0; --s) { u32 v = csum[s]; csum[s] = run; run += v; }
    }
    __syncthreads();
    const int g = t >> 2;
    u32 ex = csum[g];
    for (int j = 16*g + 15; j >= 4*t + 4; --j) ex += hist[j];
    u32 h0 = hist[4*t], h1 = hist[4*t+1], h2 = hist[4*t+2], h3 = hist[4*t+3];
    u32 st3 = ex, st2 = st3 + h3, st1 = st2 + h2, st0 = st1 + h1;
    int bl = -1;
    if      (st3 + h3 >= K_TOP) bl = 4*t + 3;
    else if (st2 + h2 >= K_TOP) bl = 4*t + 2;
    else if (st1 + h1 >= K_TOP) bl = 4*t + 1;
    else if (st0 + h0 >= K_TOP) bl = 4*t;
    if (bl >= 0) atomicMax(s_B, bl);
    hist[4*t] = st0; hist[4*t+1] = st1; hist[4*t+2] = st2; hist[4*t+3] = st3;
    cur [4*t] = st0; cur [4*t+1] = st1; cur [4*t+2] = st2; cur [4*t+3] = st3;
}

// rank within own bucket segment (cand bucket-grouped); write top-300.
__device__ __forceinline__ void rank_and_write(const u64* cand, const u32* hist,
                                               const u32* cur, u32 B, bool fine,
                                               u32 bias14, int t, int b,
                                               const float4* BX, float sx, float sy,
                                               float* out) {
    int total = (int)cur[B]; if (total > NCAND) total = NCAND;
    for (int i = t; i < total; i += 256) {
        u64 key = cand[i];
        u32 bk  = fine ? fbucket(key, bias14) : (u32)(key >> 54);
        u32 o   = (u32)(key >> 32);
        u32 idx = ~((u32)key);
        int label = (int)(idx % NCLS);
        int q     = (int)(idx / NCLS);
        float4 bx = BX[q];                     // prefetch; independent of rank
        int segS = (int)hist[bk];
        int segE = (int)cur[bk]; if (segE > NCAND) segE = NCAND;
        int r = segS;
        for (int j = segS; j < segE; ++j)
            r += (cand[j] > key) ? 1 : 0;
        if (r < K_TOP) {
            float logit = unorder_f32(o);
            float score = 1.0f / (1.0f + expf(-logit));
            float* po = out + ((size_t)b * K_TOP + r) * 6;
            po[0] = (float)label;
            po[1] = score;
            po[2] = (bx.x - 0.5f * bx.z) * sx;
            po[3] = (bx.y - 0.5f * bx.w) * sy;
            po[4] = bx.z * sx;
            po[5] = bx.w * sy;
        }
    }
}

// full two-pass fallback for batch b (degenerate data / no ws / coop-fail).
// Coarse buckets o>>22, 256 threads.
__device__ void full_fallback(const float* __restrict__ logits, int b, int t,
                              u64* cand, u32* hist, u32* cur, u32* csum, int* s_B,
                              const float4* BX, float sx, float sy,
                              float* __restrict__ out) {
    __syncthreads();
    for (int i = t; i < NBK; i += 256) { hist[i] = 0; cur[i] = 0; }
    if (t == 0) *s_B = -1;
    __syncthreads();
    const float4* L4 = (const float4*)(logits + (size_t)b * (NF4 * 4));
    for (int i = t; i < NF4; i += 256) {
        float4 v = L4[i];
        atomicAdd(&hist[order_f32(v.x) >> 22], 1u);
        atomicAdd(&hist[order_f32(v.y) >> 22], 1u);
        atomicAdd(&hist[order_f32(v.z) >> 22], 1u);
        atomicAdd(&hist[order_f32(v.w) >> 22], 1u);
    }
    __syncthreads();
    scan_buckets(hist, cur, csum, s_B, t);
    __syncthreads();
    const u32 B = (u32)*s_B;
    for (int i = t; i < NF4; i += 256) {
        float4 v = L4[i];
        float vv[4] = {v.x, v.y, v.z, v.w};
        #pragma unroll
        for (int u2 = 0; u2 < 4; ++u2) {
            u32 o = order_f32(vv[u2]);
            u32 bk = o >> 22;
            if (bk >= B) {
                u32 pos = atomicAdd(&cur[bk], 1u);
                if (pos < NCAND)
                    cand[pos] = ((u64)o << 32) |
                                (u64)(0xFFFFFFFFu - (u32)(4*i + u2));
            }
        }
    }
    __syncthreads();
    rank_and_write(cand, hist, cur, B, false, 0u, t, b, BX, sx, sy, out);
}

// ---------------- fused cooperative kernel: collect || grid.sync || select ----
__global__ __launch_bounds__(256) void fused_coop(
    const float* __restrict__ logits,
    const float* __restrict__ boxes,
    const int*   __restrict__ osz,
    u32* __restrict__ gcnt,
    u64* __restrict__ gbuf,
    float* __restrict__ out)
{
    __shared__ u64 cand[NCAND];   // 16 KB
    __shared__ u32 hist[NBK];     // 4 KB
    __shared__ u32 cur[NBK];      // 4 KB
    __shared__ u32 csum[64];
    __shared__ u32 scc[NSEG];
    __shared__ int s_B;

    const int blk  = blockIdx.x;
    const int b    = blk & (NB - 1);     // batch; XCD b%8 for all its blocks
    const int c    = blk >> 8;           // 0..3
    const int t    = threadIdx.x;
    const int w    = t >> 6;
    const int lane = t & 63;

    // ---- phase 1: collect (all 1024 blocks) ----
    {
        const float4* __restrict__ L4 =
            (const float4*)(logits + (size_t)b * (NF4 * 4));
        const int wbase = c * CHUNKF + w * WAVEF;
        u64* __restrict__ seg = gbuf + (size_t)(b * NSEG + c * 4 + w) * SEGC;
        u32 cursor = 0;
        float4 v[8];
        #pragma unroll
        for (int r = 0; r < 8; ++r) v[r] = L4[wbase + r * 64 + lane];
        #pragma unroll
        for (int r = 0; r < 8; ++r)
            cursor = wstore4(v[r], (wbase + r * 64 + lane) * 4, seg, cursor, lane);
        #pragma unroll
        for (int r = 0; r < 8; ++r) v[r] = L4[wbase + (8 + r) * 64 + lane];
        #pragma unroll
        for (int r = 0; r < 8; ++r)
            cursor = wstore4(v[r], (wbase + (8 + r) * 64 + lane) * 4, seg, cursor, lane);
        float4 a0 = L4[wbase + 16 * 64 + lane];
        float4 a1 = L4[wbase + 17 * 64 + lane];
        float4 a2 = L4[wbase + 18 * 64 + lane];
        float4 a3;
        const bool tl = (lane < 34);         // 1250 - 19*64 = 34
        if (tl) a3 = L4[wbase + 19 * 64 + lane];
        cursor = wstore4(a0, (wbase + 16 * 64 + lane) * 4, seg, cursor, lane);
        cursor = wstore4(a1, (wbase + 17 * 64 + lane) * 4, seg, cursor, lane);
        cursor = wstore4(a2, (wbase + 18 * 64 + lane) * 4, seg, cursor, lane);
        if (tl)
            cursor = wstore4(a3, (wbase + 19 * 64 + lane) * 4, seg, cursor, lane);
        if (lane == 0) gcnt[b * NSEG + c * 4 + w] = cursor;  // >SEGC = overflow
    }

    cg::this_grid().sync();

    // ---- phase 2: select (blocks c==0 only; one per batch) ----
    if (c != 0) return;
    const u32 BIAS14 = order_f32(GTHR) >> 14;

    if (t < NSEG) scc[t] = gcnt[b * NSEG + t];
    if (t == 0) s_B = -1;
    #pragma unroll
    for (int i = 0; i < 4; ++i) hist[t + 256 * i] = 0;
    __syncthreads();

    bool fast = true;
    int total = 0;
    #pragma unroll
    for (int k = 0; k < NSEG; ++k) {
        u32 x = scc[k];
        if (x > SEGC) fast = false; else total += (int)x;
    }
    fast = fast && (total >= K_TOP);

    const float sx = (float)osz[1];   // scale = [W, H, W, H]
    const float sy = (float)osz[0];
    const float4* BX = (const float4*)(boxes + (size_t)b * 4000);

    // single vectorized read: 8 keys/thread in registers (pairs t+256k)
    u64  kk[8];
    bool vv[8];
    {
        const ulonglong2* __restrict__ G2 =
            (const ulonglong2*)(gbuf + (size_t)b * NCAND);
        #pragma unroll
        for (int g = 0; g < 4; ++g) {
            const int p  = t + 256 * g;          // pair index, slots 2p,2p+1
            ulonglong2 P = G2[p];
            const int sg = p >> 6;               // (2p)>>7
            const int j  = (2 * p) & 127;
            kk[2*g]   = P.x; vv[2*g]   = (j     < (int)scc[sg]);
            kk[2*g+1] = P.y; vv[2*g+1] = (j + 1 < (int)scc[sg]);
        }
    }

    if (fast) {
        #pragma unroll
        for (int g = 0; g < 8; ++g)
            if (vv[g]) atomicAdd(&hist[fbucket(kk[g], BIAS14)], 1u);
        __syncthreads();
        scan_buckets(hist, cur, csum, &s_B, t);
        __syncthreads();
        fast = (s_B >= 1);   // B strictly above GTHR's partial bucket
    }

    if (fast) {
        const u32 B = (u32)s_B;
        #pragma unroll
        for (int g = 0; g < 8; ++g) {
            if (vv[g]) {
                u32 bk = fbucket(kk[g], BIAS14);
                if (bk >= B) { u32 p = atomicAdd(&cur[bk], 1u); cand[p] = kk[g]; }
            }
        }
        __syncthreads();
        rank_and_write(cand, hist, cur, B, true, BIAS14, t, b, BX, sx, sy, out);
    } else {
        full_fallback(logits, b, t, cand, hist, cur, csum, &s_B, BX, sx, sy, out);
    }
}

// standalone correct path (no ws / coop launch unsupported)
__global__ __launch_bounds__(256) void select_nows_kernel(
    const float* __restrict__ logits,
    const float* __restrict__ boxes,
    const int*   __restrict__ osz,
    float*       __restrict__ out)
{
    __shared__ u64 cand[NCAND];
    __shared__ u32 hist[NBK];
    __shared__ u32 cur[NBK];
    __shared__ u32 csum[64];
    __shared__ int s_B;
    const int b = blockIdx.x;
    const int t = threadIdx.x;
    const float sx = (float)osz[1];
    const float sy = (float)osz[0];
    const float4* BX = (const float4*)(boxes + (size_t)b * 4000);
    full_fallback(logits, b, t, cand, hist, cur, csum, &s_B, BX, sx, sy, out);
}

extern "C" void kernel_launch(void* const* d_in, const int* in_sizes, int n_in,
                              void* d_out, int out_size, void* d_ws, size_t ws_size,
                              hipStream_t stream) {
    const float* logits = (const float*)d_in[0];
    const float* boxes  = (const float*)d_in[1];
    const int*   osz    = (const int*)d_in[2];
    float* out = (float*)d_out;

    const size_t need = 65536 + (size_t)NB * NCAND * sizeof(u64);   // ~4.3 MB
    bool done = false;
    if (ws_size >= need) {
        u32* gcnt = (u32*)d_ws;                          // NB*NSEG u32 = 16 KB
        u64* gbuf = (u64*)((char*)d_ws + 65536);
        void* args[] = { (void*)&logits, (void*)&boxes, (void*)&osz,
                         (void*)&gcnt, (void*)&gbuf, (void*)&out };
        hipError_t err = hipLaunchCooperativeKernel(
            (const void*)fused_coop, dim3(NB * BPB), dim3(256), args, 0, stream);
        done = (err == hipSuccess);
    }
    if (!done)
        select_nows_kernel<<<dim3(NB), dim3(256), 0, stream>>>(logits, boxes, osz, out);
}

// Round 16
// 25.346 us; speedup vs baseline: 6.5110x; 6.5110x over previous
//
#include <hip/hip_runtime.h>

#define K_TOP  300
#define NCLS   80
#define NB     256
#define NF4    20000       // float4 per batch (80000 floats)
#define GTHR   2.2f        // static collect threshold; rank-300 sits at z~2.67
#define SEGC   128         // per-wave LDS segment capacity (expect ~69 +/- 8.3, 7 sigma)
#define NWAVE  16          // waves per block
#define NCAND  2048        // NWAVE*SEGC
#define NBK    1024        // bucket count

typedef unsigned int       u32;
typedef unsigned long long u64;

__device__ __forceinline__ u32 order_f32(float f) {
    u32 u = __float_as_uint(f);
    return u ^ ((u >> 31) ? 0xFFFFFFFFu : 0x80000000u);
}
__device__ __forceinline__ float unorder_f32(u32 u) {
    u32 v = (u & 0x80000000u) ? (u ^ 0x80000000u) : ~u;
    return __uint_as_float(v);
}

// fine bucket: (o>>14) - bias, clamped to [0,1023]; monotone in key
__device__ __forceinline__ u32 fbucket(u64 key, u32 bias14) {
    u32 d = (u32)(key >> 46) - bias14;
    return (d > 1023u) ? 1023u : d;
}

// ballot-aggregated per-wave LDS store: wave-uniform cursor, no atomics.
// ALL 64 lanes must call (collective ballot); losers pass win=false via v<GTHR.
__device__ __forceinline__ u32 wstore(float v, int idx, u64* __restrict__ seg,
                                      u32 cursor, int lane) {
    const bool win = (v >= GTHR);
    const u64 mask = __ballot(win);
    if (mask) {
        if (win) {
            u32 pos = cursor + (u32)__popcll(mask & ((1ull << lane) - 1ull));
            if (pos < SEGC) {
                u32 o = order_f32(v);
                seg[pos] = ((u64)o << 32) | (u64)(0xFFFFFFFFu - (u32)idx);
            }
        }
        cursor += (u32)__popcll(mask);
    }
    return cursor;
}
__device__ __forceinline__ u32 wstore4(float4 v, int i4, u64* __restrict__ seg,
                                       u32 cursor, int lane) {
    cursor = wstore(v.x, i4 + 0, seg, cursor, lane);
    cursor = wstore(v.y, i4 + 1, seg, cursor, lane);
    cursor = wstore(v.z, i4 + 2, seg, cursor, lane);
    cursor = wstore(v.w, i4 + 3, seg, cursor, lane);
    return cursor;
}

// Parallel exclusive-suffix scan over NBK=1024 buckets, 1 bucket/thread,
// shfl-based (proven R11-R14). On return hist[t]=cur[t]=ex, *s_B = max t
// with suffix(>=t) >= K_TOP. Caller barriers before/after.
__device__ __forceinline__ void scan1024(u32* hist, u32* cur, u32* wsum,
                                         int* s_B, int t) {
    const int lane = t & 63, w = t >> 6;
    const u32 h = hist[t];
    u32 s = h;
    #pragma unroll
    for (int off = 1; off < 64; off <<= 1) {   // inclusive suffix within wave
        u32 v = (u32)__shfl_down((int)s, off);
        if (lane + off < 64) s += v;
    }
    if (lane == 0) wsum[w] = s;
    __syncthreads();
    u32 wexc = 0;
    #pragma unroll
    for (int j = 0; j < 16; ++j)
        if (j > w) wexc += wsum[j];
    const u32 incl = s + wexc;
    const u32 ex   = incl - h;
    if (incl >= K_TOP) atomicMax(s_B, t);
    hist[t] = ex;
    cur[t]  = ex;
}

// rank within own bucket segment (cand bucket-grouped); write top-300.
__device__ __forceinline__ void rank_and_write(const u64* cand, const u32* hist,
                                               const u32* cur, u32 B, bool fine,
                                               u32 bias14, int t, int b,
                                               const float4* BX, float sx, float sy,
                                               float* out) {
    int total = (int)cur[B]; if (total > NCAND) total = NCAND;
    for (int i = t; i < total; i += 1024) {
        u64 key = cand[i];
        u32 bk  = fine ? fbucket(key, bias14) : (u32)(key >> 54);
        u32 o   = (u32)(key >> 32);
        u32 idx = ~((u32)key);
        int label = (int)(idx % NCLS);
        int q     = (int)(idx / NCLS);
        float4 bx = BX[q];                     // prefetch; independent of rank
        int segS = (int)hist[bk];
        int segE = (int)cur[bk]; if (segE > NCAND) segE = NCAND;
        int r = segS;
        for (int j = segS; j < segE; ++j)
            r += (cand[j] > key) ? 1 : 0;
        if (r < K_TOP) {
            float logit = unorder_f32(o);
            float score = 1.0f / (1.0f + expf(-logit));
            float* po = out + ((size_t)b * K_TOP + r) * 6;
            po[0] = (float)label;
            po[1] = score;
            po[2] = (bx.x - 0.5f * bx.z) * sx;
            po[3] = (bx.y - 0.5f * bx.w) * sy;
            po[4] = bx.z * sx;
            po[5] = bx.w * sy;
        }
    }
}

// full two-pass fallback for batch b (degenerate data only).
// Coarse buckets o>>22, 1024 threads.
__device__ void full_fallback(const float* __restrict__ logits, int b, int t,
                              u64* cand, u32* hist, u32* cur, u32* wsum, int* s_B,
                              const float4* BX, float sx, float sy,
                              float* __restrict__ out) {
    __syncthreads();
    hist[t] = 0; cur[t] = 0;
    if (t == 0) *s_B = -1;
    __syncthreads();
    const float4* L4 = (const float4*)(logits + (size_t)b * (NF4 * 4));
    for (int i = t; i < NF4; i += 1024) {
        float4 v = L4[i];
        atomicAdd(&hist[order_f32(v.x) >> 22], 1u);
        atomicAdd(&hist[order_f32(v.y) >> 22], 1u);
        atomicAdd(&hist[order_f32(v.z) >> 22], 1u);
        atomicAdd(&hist[order_f32(v.w) >> 22], 1u);
    }
    __syncthreads();
    scan1024(hist, cur, wsum, s_B, t);
    __syncthreads();
    const u32 B = (u32)*s_B;
    for (int i = t; i < NF4; i += 1024) {
        float4 v = L4[i];
        float vv[4] = {v.x, v.y, v.z, v.w};
        #pragma unroll
        for (int u2 = 0; u2 < 4; ++u2) {
            u32 o = order_f32(vv[u2]);
            u32 bk = o >> 22;
            if (bk >= B) {
                u32 pos = atomicAdd(&cur[bk], 1u);
                if (pos < NCAND)
                    cand[pos] = ((u64)o << 32) |
                                (u64)(0xFFFFFFFFu - (u32)(4*i + u2));
            }
        }
    }
    __syncthreads();
    rank_and_write(cand, hist, cur, B, false, 0u, t, b, BX, sx, sy, out);
}

// ---------------- monolithic: collect-to-LDS + select, one node, no ws ----------------
__global__ __launch_bounds__(1024) void mono_kernel(
    const float* __restrict__ logits,
    const float* __restrict__ boxes,
    const int*   __restrict__ osz,
    float*       __restrict__ out)
{
    __shared__ u64 segbuf[NCAND];   // 16 KB: 16 waves x 128 slots
    __shared__ u64 cand[NCAND];     // 16 KB: bucket-grouped candidates
    __shared__ u32 hist[NBK];       // 4 KB
    __shared__ u32 cur[NBK];        // 4 KB
    __shared__ u32 wsum[16];
    __shared__ u32 scc[NWAVE];
    __shared__ int s_B;

    const int b    = blockIdx.x;
    const int t    = threadIdx.x;
    const int w    = t >> 6;
    const int lane = t & 63;
    const u32 BIAS14 = order_f32(GTHR) >> 14;

    hist[t] = 0;                    // t spans exactly NBK; no barrier needed yet
    if (t == 0) s_B = -1;

    // ---- collect: per-wave ballot segments in LDS; no atomics, no barriers ----
    {
        const float4* __restrict__ L4 =
            (const float4*)(logits + (size_t)b * (NF4 * 4));
        u64* __restrict__ seg = segbuf + w * SEGC;
        u32 cursor = 0;
        float4 v[8];
        // rounds 0-7
        #pragma unroll
        for (int r = 0; r < 8; ++r) v[r] = L4[t + r * 1024];
        #pragma unroll
        for (int r = 0; r < 8; ++r)
            cursor = wstore4(v[r], (t + r * 1024) * 4, seg, cursor, lane);
        // rounds 8-15
        #pragma unroll
        for (int r = 0; r < 8; ++r) v[r] = L4[t + (8 + r) * 1024];
        #pragma unroll
        for (int r = 0; r < 8; ++r)
            cursor = wstore4(v[r], (t + (8 + r) * 1024) * 4, seg, cursor, lane);
        // rounds 16-18 + ragged tail (slots 19456..19999, threads 0..543)
        float4 a0 = L4[t + 16 * 1024];
        float4 a1 = L4[t + 17 * 1024];
        float4 a2 = L4[t + 18 * 1024];
        cursor = wstore4(a0, (t + 16 * 1024) * 4, seg, cursor, lane);
        cursor = wstore4(a1, (t + 17 * 1024) * 4, seg, cursor, lane);
        cursor = wstore4(a2, (t + 18 * 1024) * 4, seg, cursor, lane);
        if (w <= 8) {               // wave-uniform branch; wave 8 partially valid
            const bool tl = (t < 544);
            float4 a3 = tl ? L4[19456 + t]
                           : make_float4(-1e30f, -1e30f, -1e30f, -1e30f);
            cursor = wstore4(a3, (19456 + t) * 4, seg, cursor, lane);
        }
        if (lane == 0) scc[w] = cursor;   // > SEGC signals overflow -> fallback
    }
    __syncthreads();

    bool fast = true;
    int total = 0;
    #pragma unroll
    for (int k = 0; k < NWAVE; ++k) {
        u32 x = scc[k];
        if (x > SEGC) fast = false; else total += (int)x;
    }
    fast = fast && (total >= K_TOP);

    const float sx = (float)osz[1];   // scale = [W, H, W, H]
    const float sy = (float)osz[0];
    const float4* BX = (const float4*)(boxes + (size_t)b * 4000);

    // each thread owns LDS slots 2t, 2t+1 (same wave segment; SEGC even)
    u64 k0, k1;
    bool v0, v1;
    {
        const int sg = t >> 6;          // (2t)/128
        const int j  = (2 * t) & 127;
        k0 = segbuf[2 * t];
        k1 = segbuf[2 * t + 1];
        v0 = (j     < (int)scc[sg]);
        v1 = (j + 1 < (int)scc[sg]);
    }

    if (fast) {
        // fine-bucket histogram (threshold bucket ~10 keys -> low contention)
        if (v0) atomicAdd(&hist[fbucket(k0, BIAS14)], 1u);
        if (v1) atomicAdd(&hist[fbucket(k1, BIAS14)], 1u);
        __syncthreads();
        scan1024(hist, cur, wsum, &s_B, t);
        __syncthreads();
        fast = (s_B >= 1);   // B strictly above GTHR's partial bucket
    }

    if (fast) {
        const u32 B = (u32)s_B;
        // scatter bucket-grouped, ONLY buckets >= B (~305 keys)
        if (v0) { u32 bk = fbucket(k0, BIAS14);
                  if (bk >= B) { u32 p = atomicAdd(&cur[bk], 1u); cand[p] = k0; } }
        if (v1) { u32 bk = fbucket(k1, BIAS14);
                  if (bk >= B) { u32 p = atomicAdd(&cur[bk], 1u); cand[p] = k1; } }
        __syncthreads();
        rank_and_write(cand, hist, cur, B, true, BIAS14, t, b, BX, sx, sy, out);
    } else {
        full_fallback(logits, b, t, cand, hist, cur, wsum, &s_B, BX, sx, sy, out);
    }
}

extern "C" void kernel_launch(void* const* d_in, const int* in_sizes, int n_in,
                              void* d_out, int out_size, void* d_ws, size_t ws_size,
                              hipStream_t stream) {
    const float* logits = (const float*)d_in[0];
    const float* boxes  = (const float*)d_in[1];
    const int*   osz    = (const int*)d_in[2];
    float* out = (float*)d_out;
    mono_kernel<<<dim3(NB), dim3(1024), 0, stream>>>(logits, boxes, osz, out);
}